// Round 16
// baseline (498.570 us; speedup 1.0000x reference)
//
#include <hip/hip_runtime.h>

#define N_PTS    20000
#define M_NODES  1024
#define BATCH    4
#define NNODE    (BATCH * M_NODES)   // 4096
#define K_NN     50
#define D_MODEL  256
#define NPF      84
#define CAPQ     768                 // per-wave candidate list capacity
#define SELWIN   160                 // rank window upper bound
#define G        32                  // grid cells per dim
#define NCELL    (G * G * G)         // 32768 per batch
#define H        0.25f               // cell size
#define GBASE    (-4.0f)

__device__ __forceinline__ float signed_angle(float ax, float ay, float az,
                                              float bx, float by, float bz) {
    float cx = ay * bz - az * by;
    float cy = az * bx - ax * bz;
    float cz = ax * by - ay * bx;
    float s = sqrtf(cx * cx + cy * cy + cz * cz);
    float c = ax * bx + ay * by + az * bz;
    float a = atan2f(s, c);
    return (c < 0.0f) ? -a : a;
}

__device__ __forceinline__ int clampg(int v) { return min(max(v, 0), G - 1); }

__device__ __forceinline__ int cell_of(float x, float y, float z) {
    int cx = clampg((int)floorf((x - GBASE) * 4.0f));
    int cy = clampg((int)floorf((y - GBASE) * 4.0f));
    int cz = clampg((int)floorf((z - GBASE) * 4.0f));
    return (cz * G + cy) * G + cx;
}

// ===== bin count =====
__global__ __launch_bounds__(256) void k_count(
    const float* __restrict__ points, int* __restrict__ gcnt)
{
    int gid = blockIdx.x * 256 + threadIdx.x;
    if (gid >= BATCH * N_PTS) return;
    int b = gid / N_PTS;
    int i = gid - b * N_PTS;
    const float* p = points + (size_t)b * N_PTS * 3 + (size_t)i * 3;
    atomicAdd(&gcnt[b * NCELL + cell_of(p[0], p[1], p[2])], 1);
}

// ===== exclusive scan per batch (1 block per batch) =====
__global__ __launch_bounds__(256) void k_scan(
    const int* __restrict__ gcnt, int* __restrict__ gofs, int* __restrict__ gcur)
{
    __shared__ int lds[256];
    const int base = blockIdx.x * NCELL;
    const int tid = threadIdx.x;
    const int SEG = NCELL / 256;   // 128
    int s = 0;
    for (int j = 0; j < SEG; ++j) s += gcnt[base + tid * SEG + j];
    lds[tid] = s;
    __syncthreads();
    for (int off = 1; off < 256; off <<= 1) {
        int v = (tid >= off) ? lds[tid - off] : 0;
        __syncthreads();
        lds[tid] += v;
        __syncthreads();
    }
    int run = lds[tid] - s;   // exclusive
    for (int j = 0; j < SEG; ++j) {
        int idx = base + tid * SEG + j;
        int c = gcnt[idx];
        gofs[idx] = run;
        gcur[idx] = run;
        run += c;
    }
}

// ===== scatter into binned array (x,y,z, idx-bits) =====
__global__ __launch_bounds__(256) void k_scatter(
    const float* __restrict__ points, int* __restrict__ gcur,
    float4* __restrict__ binned)
{
    int gid = blockIdx.x * 256 + threadIdx.x;
    if (gid >= BATCH * N_PTS) return;
    int b = gid / N_PTS;
    int i = gid - b * N_PTS;
    const float* p = points + (size_t)b * N_PTS * 3 + (size_t)i * 3;
    float x = p[0], y = p[1], z = p[2];
    int pos = atomicAdd(&gcur[b * NCELL + cell_of(x, y, z)], 1);
    binned[(size_t)b * N_PTS + pos] = make_float4(x, y, z, __int_as_float(i));
}

// ===== query: wave-per-node shell expansion + exact top-50 + features =====
__global__ __launch_bounds__(256, 4) void k_query(
    const float* __restrict__ points, const float* __restrict__ nodes,
    const float* __restrict__ pnrm, const float* __restrict__ nnrm,
    const float* __restrict__ W, const float* __restrict__ bias,
    const int* __restrict__ gcnt, const int* __restrict__ gofs,
    const float4* __restrict__ binned, float* __restrict__ out)
{
    __shared__ unsigned long long klist_s[4][CAPQ];   // 24576 B
    __shared__ float4 f4v[4][K_NN];                   // 3200 B
    __shared__ unsigned short selidx[4][K_NN];        // 400 B

    const int tid = threadIdx.x, wv = tid >> 6, lane = tid & 63;
    const int bm = blockIdx.x * 4 + wv;
    const int b  = bm >> 10;
    const float* pts = points + (size_t)b * N_PTS * 3;
    const float* pnr = pnrm   + (size_t)b * N_PTS * 3;
    const int* cnt_b = gcnt + b * NCELL;
    const int* ofs_b = gofs + b * NCELL;
    const float4* bin_b = binned + (size_t)b * N_PTS;

    const float nx  = nodes[bm * 3 + 0];
    const float ny  = nodes[bm * 3 + 1];
    const float nz  = nodes[bm * 3 + 2];
    const float n1x = nnrm[bm * 3 + 0];
    const float n1y = nnrm[bm * 3 + 1];
    const float n1z = nnrm[bm * 3 + 2];

    unsigned long long* klist = klist_s[wv];
    if (lane < K_NN) selidx[wv][lane] = 0;    // defense vs pathological ties

    const int cix = clampg((int)floorf((nx - GBASE) * 4.0f));
    const int ciy = clampg((int)floorf((ny - GBASE) * 4.0f));
    const int ciz = clampg((int)floorf((nz - GBASE) * 4.0f));

    int run = 0, cterm = 0;
    bool ovf = false, term = false;
    unsigned long long cutk = 0;

    for (int ks = 1; ks <= G && !term; ++ks) {
        const int L = 2 * ks + 1;
        const int ncube = L * L * L;
        // pass 1: per-lane candidate count over this shell's cells
        int mycnt = 0;
        for (int ci = lane; ci < ncube; ci += 64) {
            int dz = ci / (L * L); int rem = ci - dz * L * L;
            int dy = rem / L;      int dx = rem - dy * L;
            dx -= ks; dy -= ks; dz -= ks;
            int ch = max(abs(dx), max(abs(dy), abs(dz)));
            if (ks > 1 && ch < ks) continue;                 // interior done
            int cx = cix + dx, cy = ciy + dy, cz = ciz + dz;
            if ((unsigned)cx >= G || (unsigned)cy >= G || (unsigned)cz >= G) continue;
            mycnt += cnt_b[(cz * G + cy) * G + cx];
        }
        int inc = mycnt;
        #pragma unroll
        for (int s = 1; s < 64; s <<= 1) {
            int u = __shfl_up(inc, s);
            if (lane >= s) inc += u;
        }
        int total = __shfl(inc, 63);
        if (run + total > CAPQ) { ovf = true; break; }
        int wpos = run + inc - mycnt;
        // pass 2: gather keys
        for (int ci = lane; ci < ncube; ci += 64) {
            int dz = ci / (L * L); int rem = ci - dz * L * L;
            int dy = rem / L;      int dx = rem - dy * L;
            dx -= ks; dy -= ks; dz -= ks;
            int ch = max(abs(dx), max(abs(dy), abs(dz)));
            if (ks > 1 && ch < ks) continue;
            int cx = cix + dx, cy = ciy + dy, cz = ciz + dz;
            if ((unsigned)cx >= G || (unsigned)cy >= G || (unsigned)cz >= G) continue;
            int cell = (cz * G + cy) * G + cx;
            int c = cnt_b[cell], st = ofs_b[cell];
            for (int j = 0; j < c; ++j) {
                float4 q = bin_b[st + j];
                float ddx = q.x - nx, ddy = q.y - ny, ddz = q.z - nz;
                float d2 = ddx * ddx + ddy * ddy + ddz * ddz;
                klist[wpos++] = ((unsigned long long)__float_as_uint(d2) << 32)
                                | (unsigned)__float_as_int(q.w);
            }
        }
        run += total;
        // termination: >=50 gathered strictly inside shrunk radius (k*H)^2
        float R = (float)ks * H;
        float shrink = R * R * (1.0f - 1e-5f);   // margin >> fp32 rounding
        unsigned long long ck = ((unsigned long long)__float_as_uint(shrink)) << 32;
        int c = 0;
        for (int s2 = lane; s2 < run; s2 += 64) c += (int)(klist[s2] < ck);
        for (int off = 32; off; off >>= 1) c += __shfl_down(c, off);
        c = __shfl(c, 0);
        if (c >= K_NN) { term = true; cutk = ck; cterm = c; }
    }

    int nsel = 0;
    if (!term || ovf) {
        // ---- slow path (rare): full-scan bisection repair ----
        unsigned lo = 0, hi = 0x7F800000u, good = 0;
        for (int a = 0; a < 34; ++a) {
            if (hi - lo <= 1u) { good = hi; break; }
            unsigned mid = lo + ((hi - lo) >> 1);
            float tf = __uint_as_float(mid);
            int c = 0;
            for (int i0 = lane; i0 < N_PTS; i0 += 64) {
                float dx = pts[i0 * 3 + 0] - nx;
                float dy = pts[i0 * 3 + 1] - ny;
                float dz = pts[i0 * 3 + 2] - nz;
                c += (int)(dx * dx + dy * dy + dz * dz < tf);
            }
            for (int off = 32; off; off >>= 1) c += __shfl_down(c, off);
            c = __shfl(c, 0);
            if (c >= K_NN && c <= CAPQ) { good = mid; break; }
            if (c < K_NN) lo = mid; else hi = mid;
        }
        if (!good) good = hi;
        float tf = __uint_as_float(good);
        int rr = 0;
        for (int base2 = 0; base2 < N_PTS; base2 += 64) {
            int i0 = base2 + lane;
            bool pred = false; unsigned kb2 = 0;
            if (i0 < N_PTS) {
                float dx = pts[i0 * 3 + 0] - nx;
                float dy = pts[i0 * 3 + 1] - ny;
                float dz = pts[i0 * 3 + 2] - nz;
                float d2 = dx * dx + dy * dy + dz * dz;
                kb2 = __float_as_uint(d2);
                pred = d2 < tf;
            }
            unsigned long long mask = __ballot(pred);
            if (pred) {
                int q = rr + (int)__popcll(mask & ((1ull << lane) - 1ull));
                if (q < CAPQ)
                    klist[q] = ((unsigned long long)kb2 << 32) | (unsigned)i0;
            }
            rr += (int)__popcll(mask);
        }
        nsel = rr < CAPQ ? rr : CAPQ;
    } else if (run <= SELWIN) {
        nsel = run;                                  // take-all
    } else {
        // refine to a cut with 50 <= c <= SELWIN, then in-place compact
        unsigned long long tcut = cutk;
        bool conv = (cterm <= SELWIN);
        if (!conv) {
            unsigned lo = 0, hi = (unsigned)(cutk >> 32);
            for (int it = 0; it < 32 && !conv; ++it) {
                unsigned mid = lo + ((hi - lo) >> 1);
                unsigned long long tm = ((unsigned long long)mid) << 32;
                int c = 0;
                for (int s2 = lane; s2 < run; s2 += 64) c += (int)(klist[s2] < tm);
                for (int off = 32; off; off >>= 1) c += __shfl_down(c, off);
                c = __shfl(c, 0);
                if (c >= K_NN && c <= SELWIN) { tcut = tm; conv = true; }
                else if (c < K_NN) lo = mid;
                else hi = mid;
                if (hi - lo <= 1u) break;
            }
        }
        if (conv) {
            // in-place ballot compact (dest <= src, wave-lockstep safe)
            int rr = 0;
            for (int base2 = 0; base2 < run; base2 += 64) {
                int s2 = base2 + lane;
                unsigned long long kx = (s2 < run) ? klist[s2] : ~0ull;
                bool pred = kx < tcut;
                unsigned long long mask = __ballot(pred);
                if (pred)
                    klist[rr + (int)__popcll(mask & ((1ull << lane) - 1ull))] = kx;
                rr += (int)__popcll(mask);
            }
            nsel = rr;
        } else {
            nsel = run;                              // pathological ties: rank all
        }
    }

    // ---- exact rank selection of the 50 nearest (ties -> low idx) ----
    for (int s2 = lane; s2 < nsel; s2 += 64) {
        unsigned long long mk = klist[s2];
        int rank = 0;
        for (int j = 0; j < nsel; ++j) rank += (int)(klist[j] < mk);
        if (rank < K_NN) selidx[wv][rank] = (unsigned short)mk;   // idx < 20000
    }

    // ---- PPF features (one neighbor per lane) ----
    if (lane < K_NN) {
        int i = (int)selidx[wv][lane];
        float pxx = pts[i * 3 + 0], pyy = pts[i * 3 + 1], pzz = pts[i * 3 + 2];
        float qx = pnr[i * 3 + 0], qy = pnr[i * 3 + 1], qz = pnr[i * 3 + 2];
        float ijx = pxx - nx, ijy = pyy - ny, ijz = pzz - nz;
        float d = sqrtf(ijx * ijx + ijy * ijy + ijz * ijz);
        f4v[wv][lane] = make_float4(d,
                                    signed_angle(ijx, ijy, ijz, n1x, n1y, n1z),
                                    signed_angle(-ijx, -ijy, -ijz, qx, qy, qz),
                                    signed_angle(n1x, n1y, n1z, qx, qy, qz));
    }

    // ---- glob[d] = max_k (f4[k] . W[:,d]) + b[d] ; 4 dims per lane ----
    {
        float w0[4], w1[4], w2[4], w3[4], bb[4], mx[4];
        #pragma unroll
        for (int q = 0; q < 4; ++q) {
            int d = lane + 64 * q;
            w0[q] = W[d]; w1[q] = W[D_MODEL + d];
            w2[q] = W[2 * D_MODEL + d]; w3[q] = W[3 * D_MODEL + d];
            bb[q] = bias[d]; mx[q] = -INFINITY;
        }
        #pragma unroll 5
        for (int k = 0; k < K_NN; ++k) {
            float4 f = f4v[wv][k];
            #pragma unroll
            for (int q = 0; q < 4; ++q)
                mx[q] = fmaxf(mx[q], f.x * w0[q] + f.y * w1[q] + f.z * w2[q] + f.w * w3[q]);
        }
        #pragma unroll
        for (int q = 0; q < 4; ++q)
            out[(size_t)bm * D_MODEL + lane + 64 * q] = mx[q] + bb[q];
    }

    // ---- pos_emb ----
    #pragma unroll
    for (int r = 0; r < 4; ++r) {
        int d = lane + 64 * r;
        float pv = 0.0f;
        if (d < 3 * NPF) {
            int c2 = d / NPF, rr2 = d - c2 * NPF, i = rr2 >> 1;
            float nc = (c2 == 0) ? nx : ((c2 == 1) ? ny : nz);
            const float L2_10000 = 13.287712379549449f;
            float tinv = exp2f(-L2_10000 * (float)i / 42.0f);
            float x = nc * tinv;
            pv = (rr2 & 1) ? cosf(x) : sinf(x);
        }
        out[(size_t)NNODE * D_MODEL + (size_t)bm * D_MODEL + d] = pv;
    }
}

extern "C" void kernel_launch(void* const* d_in, const int* in_sizes, int n_in,
                              void* d_out, int out_size, void* d_ws, size_t ws_size,
                              hipStream_t stream) {
    const float* points = (const float*)d_in[0];
    const float* nodes  = (const float*)d_in[1];
    const float* pn     = (const float*)d_in[2];
    const float* nn     = (const float*)d_in[3];
    const float* W      = (const float*)d_in[4];
    const float* bias   = (const float*)d_in[5];
    float* out = (float*)d_out;

    // ws: gcnt@0 (512K) | gofs@512K | gcur@1M | binned@1.5M (1.25M)
    char* ws = (char*)d_ws;
    int* gcnt = (int*)ws;
    int* gofs = (int*)(ws + (512 << 10));
    int* gcur = (int*)(ws + (1 << 20));
    float4* binned = (float4*)(ws + (3 << 19));   // 1.5 MB

    hipMemsetAsync(gcnt, 0, BATCH * NCELL * sizeof(int), stream);
    int npt_blocks = (BATCH * N_PTS + 255) / 256;
    k_count  <<<dim3(npt_blocks), dim3(256), 0, stream>>>(points, gcnt);
    k_scan   <<<dim3(BATCH),      dim3(256), 0, stream>>>(gcnt, gofs, gcur);
    k_scatter<<<dim3(npt_blocks), dim3(256), 0, stream>>>(points, gcur, binned);
    k_query  <<<dim3(NNODE / 4),  dim3(256), 0, stream>>>(points, nodes, pn, nn,
                                                          W, bias, gcnt, gofs,
                                                          binned, out);
}

// Round 17
// 267.418 us; speedup vs baseline: 1.8644x; 1.8644x over previous
//
#include <hip/hip_runtime.h>

#define N_PTS    20000
#define M_NODES  1024
#define BATCH    4
#define NNODE    (BATCH * M_NODES)   // 4096
#define K_NN     50
#define D_MODEL  256
#define NPF      84
#define CAPQ     2048                // per-node candidate list capacity
#define SELWIN   160                 // rank window upper bound
#define G        32                  // grid cells per dim
#define NCELL    (G * G * G)         // 32768 per batch
#define H        0.25f               // cell size
#define GBASE    (-4.0f)

__device__ __forceinline__ float signed_angle(float ax, float ay, float az,
                                              float bx, float by, float bz) {
    float cx = ay * bz - az * by;
    float cy = az * bx - ax * bz;
    float cz = ax * by - ay * bx;
    float s = sqrtf(cx * cx + cy * cy + cz * cz);
    float c = ax * bx + ay * by + az * bz;
    float a = atan2f(s, c);
    return (c < 0.0f) ? -a : a;
}

__device__ __forceinline__ int clampg(int v) { return min(max(v, 0), G - 1); }

__device__ __forceinline__ int cell_of(float x, float y, float z) {
    int cx = clampg((int)floorf((x - GBASE) * 4.0f));
    int cy = clampg((int)floorf((y - GBASE) * 4.0f));
    int cz = clampg((int)floorf((z - GBASE) * 4.0f));
    return (cz * G + cy) * G + cx;
}

// ===== bin count =====
__global__ __launch_bounds__(256) void k_count(
    const float* __restrict__ points, int* __restrict__ gcnt)
{
    int gid = blockIdx.x * 256 + threadIdx.x;
    if (gid >= BATCH * N_PTS) return;
    int b = gid / N_PTS;
    int i = gid - b * N_PTS;
    const float* p = points + (size_t)b * N_PTS * 3 + (size_t)i * 3;
    atomicAdd(&gcnt[b * NCELL + cell_of(p[0], p[1], p[2])], 1);
}

// ===== exclusive scan per batch (1 block per batch) =====
__global__ __launch_bounds__(256) void k_scan(
    const int* __restrict__ gcnt, int* __restrict__ gofs, int* __restrict__ gcur)
{
    __shared__ int lds[256];
    const int base = blockIdx.x * NCELL;
    const int tid = threadIdx.x;
    const int SEG = NCELL / 256;   // 128
    int s = 0;
    for (int j = 0; j < SEG; ++j) s += gcnt[base + tid * SEG + j];
    lds[tid] = s;
    __syncthreads();
    for (int off = 1; off < 256; off <<= 1) {
        int v = (tid >= off) ? lds[tid - off] : 0;
        __syncthreads();
        lds[tid] += v;
        __syncthreads();
    }
    int run = lds[tid] - s;   // exclusive
    for (int j = 0; j < SEG; ++j) {
        int idx = base + tid * SEG + j;
        int c = gcnt[idx];
        gofs[idx] = run;
        gcur[idx] = run;
        run += c;
    }
}

// ===== scatter into binned array (x,y,z, idx-bits) =====
__global__ __launch_bounds__(256) void k_scatter(
    const float* __restrict__ points, int* __restrict__ gcur,
    float4* __restrict__ binned)
{
    int gid = blockIdx.x * 256 + threadIdx.x;
    if (gid >= BATCH * N_PTS) return;
    int b = gid / N_PTS;
    int i = gid - b * N_PTS;
    const float* p = points + (size_t)b * N_PTS * 3 + (size_t)i * 3;
    float x = p[0], y = p[1], z = p[2];
    int pos = atomicAdd(&gcur[b * NCELL + cell_of(x, y, z)], 1);
    binned[(size_t)b * N_PTS + pos] = make_float4(x, y, z, __int_as_float(i));
}

// ===== query: one wave per node; shell expansion + exact top-50 =====
__global__ __launch_bounds__(64) void k_query(
    const float* __restrict__ points, const float* __restrict__ nodes,
    const float* __restrict__ pnrm, const float* __restrict__ nnrm,
    const float* __restrict__ W, const float* __restrict__ bias,
    const int* __restrict__ gcnt, const int* __restrict__ gofs,
    const float4* __restrict__ binned, float* __restrict__ out)
{
    __shared__ unsigned long long klist[CAPQ];   // 16384 B
    __shared__ float4 f4v[K_NN];                 // 800 B
    __shared__ unsigned short selidx[K_NN];      // 100 B

    const int lane = threadIdx.x;
    const int bm = blockIdx.x;
    const int b  = bm >> 10;
    const float* pts = points + (size_t)b * N_PTS * 3;
    const float* pnr = pnrm   + (size_t)b * N_PTS * 3;
    const int* cnt_b = gcnt + b * NCELL;
    const int* ofs_b = gofs + b * NCELL;
    const float4* bin_b = binned + (size_t)b * N_PTS;

    const float nx  = nodes[bm * 3 + 0];
    const float ny  = nodes[bm * 3 + 1];
    const float nz  = nodes[bm * 3 + 2];
    const float n1x = nnrm[bm * 3 + 0];
    const float n1y = nnrm[bm * 3 + 1];
    const float n1z = nnrm[bm * 3 + 2];

    if (lane < K_NN) selidx[lane] = 0;        // defense vs pathological ties

    const int cix = clampg((int)floorf((nx - GBASE) * 4.0f));
    const int ciy = clampg((int)floorf((ny - GBASE) * 4.0f));
    const int ciz = clampg((int)floorf((nz - GBASE) * 4.0f));

    int run = 0, cterm = 0, ksx = 1;
    bool ovf = false, term = false;
    unsigned long long cutk = 0;

    for (int ks = 1; ks <= G && !term; ++ks) {
        ksx = ks;
        const int L = 2 * ks + 1;
        const int ncube = L * L * L;
        // pass 1: per-lane candidate count over this shell's cells
        int mycnt = 0;
        for (int ci = lane; ci < ncube; ci += 64) {
            int dz = ci / (L * L); int rem = ci - dz * L * L;
            int dy = rem / L;      int dx = rem - dy * L;
            dx -= ks; dy -= ks; dz -= ks;
            int ch = max(abs(dx), max(abs(dy), abs(dz)));
            if (ks > 1 && ch < ks) continue;                 // interior done
            int cx = cix + dx, cy = ciy + dy, cz = ciz + dz;
            if ((unsigned)cx >= G || (unsigned)cy >= G || (unsigned)cz >= G) continue;
            mycnt += cnt_b[(cz * G + cy) * G + cx];
        }
        int inc = mycnt;
        #pragma unroll
        for (int s = 1; s < 64; s <<= 1) {
            int u = __shfl_up(inc, s);
            if (lane >= s) inc += u;
        }
        int total = __shfl(inc, 63);
        if (run + total > CAPQ) { ovf = true; break; }
        int wpos = run + inc - mycnt;
        // pass 2: gather keys
        for (int ci = lane; ci < ncube; ci += 64) {
            int dz = ci / (L * L); int rem = ci - dz * L * L;
            int dy = rem / L;      int dx = rem - dy * L;
            dx -= ks; dy -= ks; dz -= ks;
            int ch = max(abs(dx), max(abs(dy), abs(dz)));
            if (ks > 1 && ch < ks) continue;
            int cx = cix + dx, cy = ciy + dy, cz = ciz + dz;
            if ((unsigned)cx >= G || (unsigned)cy >= G || (unsigned)cz >= G) continue;
            int cell = (cz * G + cy) * G + cx;
            int c = cnt_b[cell], st = ofs_b[cell];
            for (int j = 0; j < c; ++j) {
                float4 q = bin_b[st + j];
                float ddx = q.x - nx, ddy = q.y - ny, ddz = q.z - nz;
                float d2 = ddx * ddx + ddy * ddy + ddz * ddz;
                klist[wpos++] = ((unsigned long long)__float_as_uint(d2) << 32)
                                | (unsigned)__float_as_int(q.w);
            }
        }
        run += total;
        // termination: >=50 gathered strictly inside shrunk radius (ks*H)^2
        float R = (float)ks * H;
        float shrink = R * R * (1.0f - 1e-5f);   // margin >> fp32 rounding
        unsigned long long ck = ((unsigned long long)__float_as_uint(shrink)) << 32;
        int c = 0;
        for (int s2 = lane; s2 < run; s2 += 64) c += (int)(klist[s2] < ck);
        for (int off = 32; off; off >>= 1) c += __shfl_down(c, off);
        c = __shfl(c, 0);
        if (c >= K_NN) { term = true; cutk = ck; cterm = c; }
    }

    if (!term || ovf) {
        // ---- rescue: ONE filtered full scan (complete: raw points) ----
        float R = (float)ksx * H;
        float R2s = R * R * (1.0f - 1e-5f);
        int c = 0;
        for (int i0 = lane; i0 < N_PTS; i0 += 64) {
            float dx = pts[i0 * 3 + 0] - nx;
            float dy = pts[i0 * 3 + 1] - ny;
            float dz = pts[i0 * 3 + 2] - nz;
            c += (int)(dx * dx + dy * dy + dz * dz < R2s);
        }
        for (int off = 32; off; off >>= 1) c += __shfl_down(c, off);
        c = __shfl(c, 0);
        unsigned goodb = __float_as_uint(R2s);
        if (c < K_NN || c > CAPQ) {
            // tier-3 fallback: f32-bit bisection (pathological only)
            unsigned lo = 0, hi = 0x7F800000u;
            goodb = hi;
            for (int a = 0; a < 34; ++a) {
                if (hi - lo <= 1u) { goodb = hi; break; }
                unsigned mid = lo + ((hi - lo) >> 1);
                float tf = __uint_as_float(mid);
                int cc = 0;
                for (int i0 = lane; i0 < N_PTS; i0 += 64) {
                    float dx = pts[i0 * 3 + 0] - nx;
                    float dy = pts[i0 * 3 + 1] - ny;
                    float dz = pts[i0 * 3 + 2] - nz;
                    cc += (int)(dx * dx + dy * dy + dz * dz < tf);
                }
                for (int off = 32; off; off >>= 1) cc += __shfl_down(cc, off);
                cc = __shfl(cc, 0);
                if (cc >= K_NN && cc <= CAPQ) { goodb = mid; break; }
                if (cc < K_NN) lo = mid; else hi = mid;
            }
        }
        // compact filtered keys into klist
        float tf = __uint_as_float(goodb);
        int rr = 0;
        for (int base2 = 0; base2 < N_PTS; base2 += 64) {
            int i0 = base2 + lane;
            bool pred = false; unsigned kb2 = 0;
            if (i0 < N_PTS) {
                float dx = pts[i0 * 3 + 0] - nx;
                float dy = pts[i0 * 3 + 1] - ny;
                float dz = pts[i0 * 3 + 2] - nz;
                float d2 = dx * dx + dy * dy + dz * dz;
                kb2 = __float_as_uint(d2);
                pred = d2 < tf;
            }
            unsigned long long mask = __ballot(pred);
            if (pred) {
                int q = rr + (int)__popcll(mask & ((1ull << lane) - 1ull));
                if (q < CAPQ)
                    klist[q] = ((unsigned long long)kb2 << 32) | (unsigned)i0;
            }
            rr += (int)__popcll(mask);
        }
        run = rr < CAPQ ? rr : CAPQ;
        cutk = ((unsigned long long)goodb) << 32;
        cterm = run;
    }

    // ---- select down to <= SELWIN ----
    int nsel;
    if (run <= SELWIN) {
        nsel = run;                                  // take-all
    } else {
        unsigned long long tcut = cutk;
        bool conv = (cterm <= SELWIN);
        if (!conv) {
            unsigned lo = 0, hi = (unsigned)(cutk >> 32);
            for (int it = 0; it < 32 && !conv; ++it) {
                unsigned mid = lo + ((hi - lo) >> 1);
                unsigned long long tm = ((unsigned long long)mid) << 32;
                int c = 0;
                for (int s2 = lane; s2 < run; s2 += 64) c += (int)(klist[s2] < tm);
                for (int off = 32; off; off >>= 1) c += __shfl_down(c, off);
                c = __shfl(c, 0);
                if (c >= K_NN && c <= SELWIN) { tcut = tm; conv = true; }
                else if (c < K_NN) lo = mid;
                else hi = mid;
                if (hi - lo <= 1u) break;
            }
        }
        if (conv) {
            // in-place ballot compact (dest <= src, wave-lockstep safe)
            int rr = 0;
            for (int base2 = 0; base2 < run; base2 += 64) {
                int s2 = base2 + lane;
                unsigned long long kx = (s2 < run) ? klist[s2] : ~0ull;
                bool pred = kx < tcut;
                unsigned long long mask = __ballot(pred);
                if (pred)
                    klist[rr + (int)__popcll(mask & ((1ull << lane) - 1ull))] = kx;
                rr += (int)__popcll(mask);
            }
            nsel = rr;
        } else {
            nsel = run;                              // pathological ties: rank all
        }
    }
    __syncthreads();

    // ---- exact rank selection of the 50 nearest (ties -> low idx) ----
    for (int s2 = lane; s2 < nsel; s2 += 64) {
        unsigned long long mk = klist[s2];
        int rank = 0;
        for (int j = 0; j < nsel; ++j) rank += (int)(klist[j] < mk);
        if (rank < K_NN) selidx[rank] = (unsigned short)mk;   // idx < 20000
    }
    __syncthreads();

    // ---- PPF features (one neighbor per lane) ----
    if (lane < K_NN) {
        int i = (int)selidx[lane];
        float pxx = pts[i * 3 + 0], pyy = pts[i * 3 + 1], pzz = pts[i * 3 + 2];
        float qx = pnr[i * 3 + 0], qy = pnr[i * 3 + 1], qz = pnr[i * 3 + 2];
        float ijx = pxx - nx, ijy = pyy - ny, ijz = pzz - nz;
        float d = sqrtf(ijx * ijx + ijy * ijy + ijz * ijz);
        f4v[lane] = make_float4(d,
                                signed_angle(ijx, ijy, ijz, n1x, n1y, n1z),
                                signed_angle(-ijx, -ijy, -ijz, qx, qy, qz),
                                signed_angle(n1x, n1y, n1z, qx, qy, qz));
    }
    __syncthreads();

    // ---- glob[d] = max_k (f4[k] . W[:,d]) + b[d] ; 4 dims per lane ----
    {
        float w0[4], w1[4], w2[4], w3[4], bb[4], mx[4];
        #pragma unroll
        for (int q = 0; q < 4; ++q) {
            int d = lane + 64 * q;
            w0[q] = W[d]; w1[q] = W[D_MODEL + d];
            w2[q] = W[2 * D_MODEL + d]; w3[q] = W[3 * D_MODEL + d];
            bb[q] = bias[d]; mx[q] = -INFINITY;
        }
        #pragma unroll 5
        for (int k = 0; k < K_NN; ++k) {
            float4 f = f4v[k];
            #pragma unroll
            for (int q = 0; q < 4; ++q)
                mx[q] = fmaxf(mx[q], f.x * w0[q] + f.y * w1[q] + f.z * w2[q] + f.w * w3[q]);
        }
        #pragma unroll
        for (int q = 0; q < 4; ++q)
            out[(size_t)bm * D_MODEL + lane + 64 * q] = mx[q] + bb[q];
    }

    // ---- pos_emb ----
    #pragma unroll
    for (int r = 0; r < 4; ++r) {
        int d = lane + 64 * r;
        float pv = 0.0f;
        if (d < 3 * NPF) {
            int c2 = d / NPF, rr2 = d - c2 * NPF, i = rr2 >> 1;
            float nc = (c2 == 0) ? nx : ((c2 == 1) ? ny : nz);
            const float L2_10000 = 13.287712379549449f;
            float tinv = exp2f(-L2_10000 * (float)i / 42.0f);
            float x = nc * tinv;
            pv = (rr2 & 1) ? cosf(x) : sinf(x);
        }
        out[(size_t)NNODE * D_MODEL + (size_t)bm * D_MODEL + d] = pv;
    }
}

extern "C" void kernel_launch(void* const* d_in, const int* in_sizes, int n_in,
                              void* d_out, int out_size, void* d_ws, size_t ws_size,
                              hipStream_t stream) {
    const float* points = (const float*)d_in[0];
    const float* nodes  = (const float*)d_in[1];
    const float* pn     = (const float*)d_in[2];
    const float* nn     = (const float*)d_in[3];
    const float* W      = (const float*)d_in[4];
    const float* bias   = (const float*)d_in[5];
    float* out = (float*)d_out;

    // ws: gcnt@0 (512K) | gofs@512K | gcur@1M | binned@1.5M (1.25M)
    char* ws = (char*)d_ws;
    int* gcnt = (int*)ws;
    int* gofs = (int*)(ws + (512 << 10));
    int* gcur = (int*)(ws + (1 << 20));
    float4* binned = (float4*)(ws + (3 << 19));   // 1.5 MB

    hipMemsetAsync(gcnt, 0, BATCH * NCELL * sizeof(int), stream);
    int npt_blocks = (BATCH * N_PTS + 255) / 256;
    k_count  <<<dim3(npt_blocks), dim3(256), 0, stream>>>(points, gcnt);
    k_scan   <<<dim3(BATCH),      dim3(256), 0, stream>>>(gcnt, gofs, gcur);
    k_scatter<<<dim3(npt_blocks), dim3(256), 0, stream>>>(points, gcur, binned);
    k_query  <<<dim3(NNODE),      dim3(64),  0, stream>>>(points, nodes, pn, nn,
                                                          W, bias, gcnt, gofs,
                                                          binned, out);
}